// Round 1
// baseline (33.505 us; speedup 1.0000x reference)
//
#include <hip/hip_runtime.h>

#define THETA 2.0f
#define NRHO 2048
#define NOUT 2044   // NRHO - 4

__global__ __launch_bounds__(512) void vprime_stencil_kernel(
    const float* __restrict__ rho,
    const float* __restrict__ v,
    float* __restrict__ out)
{
    __shared__ float r[NRHO];

    const int row = blockIdx.x;
    const int t   = threadIdx.x;

    const float* rrow = rho + (size_t)row * NRHO;

    // Cooperative row load: 512 threads x float4 = 2048 floats.
    float4 lo = reinterpret_cast<const float4*>(rrow)[t];
    reinterpret_cast<float4*>(r)[t] = lo;
    __syncthreads();

    if (t < 511) {
        // This thread produces outputs j0..j0+3, needs rho[j0..j0+7].
        // lo = rho[4t..4t+3] (already in regs), hi = rho[4t+4..4t+7] from LDS.
        const int j0 = t * 4;
        float4 hi = reinterpret_cast<float4*>(r)[t + 1];

        float x[8] = {lo.x, lo.y, lo.z, lo.w, hi.x, hi.y, hi.z, hi.w};

        // half-slopes hs(i) for i = j0 .. j0+5
        float hs[6];
        #pragma unroll
        for (int i = 0; i < 6; ++i) {
            float a  = THETA * (x[i + 1] - x[i]);
            float b  = 0.5f  * (x[i + 2] - x[i]);
            float c  = THETA * (x[i + 2] - x[i + 1]);
            float mn = fminf(fminf(a, b), c);
            float mx = fmaxf(fmaxf(a, b), c);
            float mm = (mn < 0.0f) ? fminf(mx, 0.0f) : mn;
            hs[i] = 0.5f * mm;
        }

        const float* vrow = v   + (size_t)row * NOUT;
        float*       orow = out + (size_t)row * NOUT;

        float4 vv = reinterpret_cast<const float4*>(vrow)[t];
        float vf[4] = {vv.x, vv.y, vv.z, vv.w};

        float res[4];
        #pragma unroll
        for (int j = 0; j < 4; ++j) {
            float rp = (x[j + 2] - x[j + 1]) + (hs[j + 1] - hs[j]);
            float rm = (x[j + 3] - x[j + 2]) - (hs[j + 2] - hs[j + 1]);
            float dr = (vf[j] < 0.0f) ? rm : rp;
            res[j] = vf[j] * dr;
        }

        reinterpret_cast<float4*>(orow)[t] =
            make_float4(res[0], res[1], res[2], res[3]);
    }
}

extern "C" void kernel_launch(void* const* d_in, const int* in_sizes, int n_in,
                              void* d_out, int out_size, void* d_ws, size_t ws_size,
                              hipStream_t stream) {
    const float* rho = (const float*)d_in[0];
    const float* v   = (const float*)d_in[1];
    float* out       = (float*)d_out;

    const int rows = in_sizes[0] / NRHO;   // 32*256 = 8192

    vprime_stencil_kernel<<<rows, 512, 0, stream>>>(rho, v, out);
}